// Round 3
// baseline (160.332 us; speedup 1.0000x reference)
//
#include <hip/hip_runtime.h>
#include <hip/hip_bf16.h>

// PriorScaleShift:
//   x:         (B=1024, S=512) int32 token ids in [0, 32000)
//   mask:      (B, S, 1) float32  (nonnegative)
//   log_scale: (1, 1, V=32000) float32
//   shift:     (1, 1, V) float32
//   out:       (B, 1, V) float32 = exp(log_scale) * presence + shift
// presence[b,v] = 1 iff sum_s mask[b,s]*[x[b,s]==v] > 0
//               = 1 iff exists s with x[b,s]==v and mask[b,s] > 0  (masks >= 0)

#define PSS_VOCAB 32000
#define PSS_SEQ   512
#define PSS_BLOCK 256
#define PSS_WORDS (PSS_VOCAB / 32)   // 1000 LDS words = 4000 B

__global__ __launch_bounds__(PSS_BLOCK)
void PriorScaleShift_47467978556092_kernel(const int* __restrict__ x,
                                           const float* __restrict__ mask,
                                           const float* __restrict__ log_scale,
                                           const float* __restrict__ shift,
                                           float* __restrict__ out) {
    __shared__ unsigned int bits[PSS_WORDS];

    const int b = blockIdx.x;
    const int t = threadIdx.x;

    // 1) zero presence bitmask
    for (int i = t; i < PSS_WORDS; i += PSS_BLOCK) bits[i] = 0u;
    __syncthreads();

    // 2) scatter: mark tokens present in this row (mask > 0 contributions only)
    const int*   xr = x    + (size_t)b * PSS_SEQ;
    const float* mr = mask + (size_t)b * PSS_SEQ;
    for (int s = t; s < PSS_SEQ; s += PSS_BLOCK) {
        const int   v = xr[s];
        const float m = mr[s];
        if (m > 0.0f) atomicOr(&bits[v >> 5], 1u << (v & 31));
    }
    __syncthreads();

    // 3) write row: out[b,v] = presence ? exp(ls[v]) + sh[v] : sh[v]
    //    vectorized float4 (V = 32000 = 8000 * 4); 4 consecutive bits always
    //    live in one word since v0 % 4 == 0.
    const float4* ls4 = (const float4*)log_scale;
    const float4* sh4 = (const float4*)shift;
    float4* o4 = (float4*)(out + (size_t)b * PSS_VOCAB);

    for (int i = t; i < PSS_VOCAB / 4; i += PSS_BLOCK) {
        const float4 ls = ls4[i];
        const float4 sh = sh4[i];
        const int v0 = i << 2;
        const unsigned int w = bits[v0 >> 5] >> (v0 & 31);
        float4 r;
        r.x = (w & 1u) ? (expf(ls.x) + sh.x) : sh.x;
        r.y = (w & 2u) ? (expf(ls.y) + sh.y) : sh.y;
        r.z = (w & 4u) ? (expf(ls.z) + sh.z) : sh.z;
        r.w = (w & 8u) ? (expf(ls.w) + sh.w) : sh.w;
        o4[i] = r;
    }
}

extern "C" void kernel_launch(void* const* d_in, const int* in_sizes, int n_in,
                              void* d_out, int out_size, void* d_ws, size_t ws_size,
                              hipStream_t stream) {
    const int*   x         = (const int*)d_in[0];
    const float* mask      = (const float*)d_in[1];
    const float* log_scale = (const float*)d_in[2];
    const float* shift     = (const float*)d_in[3];
    float* out = (float*)d_out;

    const int batch = in_sizes[0] / PSS_SEQ;   // 1024

    PriorScaleShift_47467978556092_kernel<<<batch, PSS_BLOCK, 0, stream>>>(
        x, mask, log_scale, shift, out);
}

// Round 7
// 152.513 us; speedup vs baseline: 1.0513x; 1.0513x over previous
//
#include <hip/hip_runtime.h>
#include <hip/hip_bf16.h>

// PriorScaleShift:
//   x:         (B=1024, S=512) int32 token ids in [0, 32000)
//   mask:      (B, S, 1) float32  (nonnegative, uniform [0,1))
//   log_scale: (1, 1, V=32000) float32
//   shift:     (1, 1, V) float32
//   out:       (B, 1, V) float32 = exp(log_scale) * presence + shift
// presence[b,v] = 1 iff exists s: x[b,s]==v and mask[b,s] > 0 (all masks >= 0,
// so sum > 0 <=> any term > 0 — matches reference's counts > 0).
//
// Structure:
//   kernel 1 (tiny): tA[v] = expf(ls[v]) + sh[v]; tB[v] = sh[v]  -> d_ws
//   kernel 2 (main): one block per (row, vocab-chunk); LDS presence bitmask;
//                    out4 = bit ? tA4 : tB4, nontemporal 16B stores.
// Uses clang ext_vector_type float4 (v4f) because __builtin_nontemporal_store
// rejects HIP_vector_type float4.

#define PSS_VOCAB  32000
#define PSS_SEQ    512
#define PSS_BLOCK  256
#define PSS_CHUNKS 4
#define PSS_CHUNK  (PSS_VOCAB / PSS_CHUNKS)   // 8000
#define PSS_CWORDS (PSS_CHUNK / 32)           // 250 LDS words = 1000 B
#define PSS_CF4    (PSS_CHUNK / 4)            // 2000 float4 per chunk

typedef float v4f __attribute__((ext_vector_type(4)));

__global__ __launch_bounds__(PSS_BLOCK)
void pss_tables_kernel(const float* __restrict__ ls, const float* __restrict__ sh,
                       float* __restrict__ tA, float* __restrict__ tB) {
    const int i = blockIdx.x * PSS_BLOCK + threadIdx.x;
    if (i < PSS_VOCAB) {
        const float l = ls[i];
        const float s = sh[i];
        tA[i] = expf(l) + s;   // value when token present
        tB[i] = s;             // value when absent
    }
}

__global__ __launch_bounds__(PSS_BLOCK)
void PriorScaleShift_47467978556092_kernel(const int* __restrict__ x,
                                           const float* __restrict__ mask,
                                           const float* __restrict__ tA,
                                           const float* __restrict__ tB,
                                           float* __restrict__ out) {
    __shared__ unsigned int bits[PSS_CWORDS];

    const int bid  = blockIdx.x;
    const int row  = bid >> 2;                 // bid / PSS_CHUNKS
    const int c    = bid & (PSS_CHUNKS - 1);
    const int t    = threadIdx.x;
    const int vbase = c * PSS_CHUNK;

    // 1) zero this chunk's presence bitmask (250 words < 256 threads)
    if (t < PSS_CWORDS) bits[t] = 0u;
    __syncthreads();

    // 2) scan the row's tokens; mark ones falling in this vocab chunk
    const int*   xr = x    + (size_t)row * PSS_SEQ;
    const float* mr = mask + (size_t)row * PSS_SEQ;
    #pragma unroll
    for (int s = t; s < PSS_SEQ; s += PSS_BLOCK) {
        const int   rel = xr[s] - vbase;
        const float m   = mr[s];
        if (m > 0.0f && (unsigned)rel < (unsigned)PSS_CHUNK)
            atomicOr(&bits[rel >> 5], 1u << (rel & 31));
    }
    __syncthreads();

    // 3) streaming select-write: out = bit ? tA : tB (both L2-resident)
    const v4f* a4 = (const v4f*)(tA + vbase);
    const v4f* b4 = (const v4f*)(tB + vbase);
    v4f* o4 = (v4f*)(out + (size_t)row * PSS_VOCAB + vbase);

    for (int i = t; i < PSS_CF4; i += PSS_BLOCK) {
        const v4f a = a4[i];
        const v4f b = b4[i];
        // float4 i covers bits 4i..4i+3 -> word i>>3, shift (i&7)*4
        const unsigned int w = bits[i >> 3] >> ((i & 7) << 2);
        v4f r;
        r.x = (w & 1u) ? a.x : b.x;
        r.y = (w & 2u) ? a.y : b.y;
        r.z = (w & 4u) ? a.z : b.z;
        r.w = (w & 8u) ? a.w : b.w;
        __builtin_nontemporal_store(r, &o4[i]);
    }
}

extern "C" void kernel_launch(void* const* d_in, const int* in_sizes, int n_in,
                              void* d_out, int out_size, void* d_ws, size_t ws_size,
                              hipStream_t stream) {
    const int*   x         = (const int*)d_in[0];
    const float* mask      = (const float*)d_in[1];
    const float* log_scale = (const float*)d_in[2];
    const float* shift     = (const float*)d_in[3];
    float* out = (float*)d_out;

    float* tA = (float*)d_ws;                 // 32000 floats
    float* tB = tA + PSS_VOCAB;               // 32000 floats (256 KB total)

    const int batch = in_sizes[0] / PSS_SEQ;  // 1024

    pss_tables_kernel<<<(PSS_VOCAB + PSS_BLOCK - 1) / PSS_BLOCK, PSS_BLOCK, 0, stream>>>(
        log_scale, shift, tA, tB);

    PriorScaleShift_47467978556092_kernel<<<batch * PSS_CHUNKS, PSS_BLOCK, 0, stream>>>(
        x, mask, tA, tB, out);
}